// Round 2
// baseline (502.746 us; speedup 1.0000x reference)
//
#include <hip/hip_runtime.h>

#define NC 21
#define NB 8
#define HW (512*512)
#define EPS 1e-8f
#define NREP 8

// Each block: 1024 consecutive pixels of one batch image. Each thread: 4 pixels
// via float4. Argmax over NC channels (strict >, ascending c => first-max
// tie-break, matches jnp.argmax).
//
// Round-3 changes vs the 487 us kernel:
//  (1) Round-2 post-mortem: VGPR_Count 32->28 with identical dur/BW proved the
//      machine scheduler re-interleaved the 7-deep load batches to minimize
//      register pressure (load->compare->load->compare), keeping ~1 load in
//      flight per wave => 650 GB/s, VALUBusy 1.8%, pure vmcnt stall.
//  (2) Fix: issue ALL 21 plane loads, then __builtin_amdgcn_sched_barrier(0)
//      (a hard fence the scheduler cannot move across), then consume. Same for
//      the 21 target loads. ~21 KB in flight per wave; needed for full HBM BW
//      is only ~9.4 KB/CU. Expect VGPR ~110-130 (4 waves/SIMD) -- trading
//      occupancy for per-wave MLP, which is the right trade at 8% BW.
//  (3) LDS replicas 4 -> 8 (t&7): 8 lanes per replica scatter into 21 columns
//      => expected max same-address collision ~2. Replica stride 441 words
//      (441 mod 32 = 25) de-aliases banks. 14 KB LDS/block, no occupancy cost
//      at 4 blocks/CU.
__global__ __launch_bounds__(256) void cm_accum(const float* __restrict__ input,
                                                const float* __restrict__ target,
                                                float* __restrict__ cm /*[NB][NC][NC]*/) {
    __shared__ float scm[NREP][NC * NC];
    const int t = threadIdx.x;
    for (int i = t; i < NREP * NC * NC; i += 256) ((float*)scm)[i] = 0.0f;
    __syncthreads();

    const int b    = blockIdx.x >> 8;    // 256 tiles per batch
    const int tile = blockIdx.x & 255;
    const int q    = (tile << 8) + t;    // float4 index within a channel plane

    const float4* ip = (const float4*)(input  + (size_t)b * NC * HW);
    const float4* tp = (const float4*)(target + (size_t)b * NC * HW);
    const int plane4 = HW / 4;

    // ---- Phase 1: issue ALL 21 input loads, fence, then argmax ----
    float4 v[NC];
    #pragma unroll
    for (int c = 0; c < NC; ++c) v[c] = ip[c * plane4 + q];
    __builtin_amdgcn_sched_barrier(0);   // nothing crosses: all loads in flight

    float4 m = v[0];
    int jx = 0, jy = 0, jz = 0, jw = 0;
    #pragma unroll
    for (int c = 1; c < NC; ++c) {
        if (v[c].x > m.x) { m.x = v[c].x; jx = c; }
        if (v[c].y > m.y) { m.y = v[c].y; jy = c; }
        if (v[c].z > m.z) { m.z = v[c].z; jz = c; }
        if (v[c].w > m.w) { m.w = v[c].w; jw = c; }
    }

    // ---- Phase 2: issue ALL 21 target loads, fence, then LDS scatter ----
    float4 y[NC];
    #pragma unroll
    for (int c = 0; c < NC; ++c) y[c] = tp[c * plane4 + q];
    __builtin_amdgcn_sched_barrier(0);

    float* my = scm[t & (NREP - 1)];
    #pragma unroll
    for (int c = 0; c < NC; ++c) {
        const int row = c * NC;
        atomicAdd(&my[row + jx], y[c].x);
        atomicAdd(&my[row + jy], y[c].y);
        atomicAdd(&my[row + jz], y[c].z);
        atomicAdd(&my[row + jw], y[c].w);
    }
    __syncthreads();

    // flush all 441 entries (strided loop: 441 > 256 threads)
    for (int i = t; i < NC * NC; i += 256) {
        float s = 0.0f;
        #pragma unroll
        for (int r = 0; r < NREP; ++r) s += scm[r][i];
        atomicAdd(&cm[b * NC * NC + i], s);
    }
}

// rowsum[b,i] = sum_j cm[b,i,j] (exact identity: one-hot sums to 1 per pixel),
// out[i,j] = mean_b cm[b,i,j] / (rowsum[b,i] + EPS)
__global__ __launch_bounds__(512) void cm_final(const float* __restrict__ cm,
                                                float* __restrict__ out) {
    __shared__ float rs[NB * NC];
    const int t = threadIdx.x;
    if (t < NB * NC) {
        const int b = t / NC, i = t % NC;
        float s = 0.0f;
        for (int j = 0; j < NC; ++j) s += cm[b * NC * NC + i * NC + j];
        rs[t] = s + EPS;
    }
    __syncthreads();
    if (t < NC * NC) {
        const int i = t / NC;
        float acc = 0.0f;
        for (int b = 0; b < NB; ++b) acc += cm[b * NC * NC + t] / rs[b * NC + i];
        out[t] = acc * (1.0f / NB);
    }
}

extern "C" void kernel_launch(void* const* d_in, const int* in_sizes, int n_in,
                              void* d_out, int out_size, void* d_ws, size_t ws_size,
                              hipStream_t stream) {
    const float* input  = (const float*)d_in[0];
    const float* target = (const float*)d_in[1];
    float* out = (float*)d_out;
    float* cm  = (float*)d_ws;   // NB*NC*NC floats

    hipMemsetAsync(cm, 0, NB * NC * NC * sizeof(float), stream);
    cm_accum<<<NB * 256, 256, 0, stream>>>(input, target, cm);
    cm_final<<<1, 512, 0, stream>>>(cm, out);
}